// Round 5
// baseline (101.390 us; speedup 1.0000x reference)
//
#include <hip/hip_runtime.h>
#include <math.h>

// QuGCN pipeline v4:
//   K1 build_quarter : 1024 waves simulate 256 basis states through EACH layer
//                      (U = U3*U2*U1*U0; M0 fusion carries RZ124 across cuts).
//   K2 combine_pair  : T1 = U1*U0 and T2 = U3*U2 (512 blocks, fp32 complex).
//   K3 combine_final : U = T2*T1, emitted as bf16 [re;im] rows for MFMA.
//   K4 mfma_eval     : amps = U*x via mfma_f32_16x16x32_bf16 (fp32 accum),
//                      fused |amp|^2 -> <Z_q> -> normalize -> linear head.

namespace {

constexpr int NSAMP = 4096;
constexpr int NW_L  = 132;

// ---------- compile-time trig ----------
constexpr double PI_D   = 3.14159265358979323846264338327950288;
constexpr double TWO_PI = 6.28318530717958647692528676655900577;

constexpr double red_pm_pi(double x) {
  double k = x / TWO_PI;
  long long ki = (long long)k;
  double r = x - (double)ki * TWO_PI;
  if (r > PI_D)  r -= TWO_PI;
  if (r < -PI_D) r += TWO_PI;
  return r;
}
constexpr double csin(double x) {
  double r = red_pm_pi(x), r2 = r * r, term = r, sum = r;
  for (int n = 1; n <= 13; ++n) { term *= -r2 / (double)((2*n)*(2*n+1)); sum += term; }
  return sum;
}
constexpr double ccos(double x) {
  double r = red_pm_pi(x), r2 = r * r, term = 1.0, sum = 1.0;
  for (int n = 1; n <= 13; ++n) { term *= -r2 / (double)((2*n-1)*(2*n)); sum += term; }
  return sum;
}

constexpr int PC[28] = {0,1,2,3,4,5,6, 0,1,2,3,4,5, 0,1,2,3,4, 0,1,2,3, 0,1,2, 0,1, 0};
constexpr int PT[28] = {1,2,3,4,5,6,7, 2,3,4,5,6,7, 3,4,5,6,7, 4,5,6,7, 5,6,7, 6,7, 7};

struct Tbl28 { float c[28]; float s[28]; };
constexpr Tbl28 mk_tbl(int base) {
  Tbl28 t{};
  for (int i = 0; i < 28; ++i) {
    double a = 0.5 * (double)(base + i);
    t.c[i] = (float)ccos(a);
    t.s[i] = (float)csin(a);
  }
  return t;
}
constexpr Tbl28 T_CRY = mk_tbl(8);
constexpr Tbl28 T_CRX = mk_tbl(52);

struct DTbl { float v[512]; };
constexpr DTbl mk_dcrz() {
  DTbl t{};
  for (int s = 0; s < 256; ++s) {
    double psi = 0.0;
    for (int i = 0; i < 28; ++i) {
      const int pc = 7 - PC[i], pt = 7 - PT[i];
      if ((s >> pc) & 1) {
        const double half = 0.5 * (double)(96 + i);
        psi += ((s >> pt) & 1) ? half : -half;
      }
    }
    t.v[2*s]   = (float)ccos(psi);
    t.v[2*s+1] = (float)csin(psi);
  }
  return t;
}
__device__ constexpr DTbl D_CRZ = mk_dcrz();

// ---------- gate appliers (verified R2-R4) ----------
__device__ __forceinline__ void gen_cross(float* ar, float* ai, int lane, int sh,
                                          float m00r, float m00i, float m01r, float m01i) {
  const int lm = 1 << sh;
  const int bbit = (lane >> sh) & 1;
  const float dr = m00r;
  const float di = bbit ? -m00i : m00i;
  const float g  = bbit ? -m01r : m01r;
  const float h  = m01i;
#pragma unroll
  for (int r = 0; r < 4; ++r) {
    float pr = __shfl_xor(ar[r], lm, 64);
    float pi = __shfl_xor(ai[r], lm, 64);
    float mr = ar[r], mi = ai[r];
    ar[r] = dr*mr - di*mi + g*pr - h*pi;
    ai[r] = dr*mi + di*mr + g*pi + h*pr;
  }
}
__device__ __forceinline__ void gen_local(float* ar, float* ai, int p,
                                          float m00r, float m00i, float m01r, float m01i) {
  const int m = 1 << p;
#pragma unroll
  for (int r0 = 0; r0 < 4; ++r0) {
    if (!(r0 & m)) {
      const int r1 = r0 | m;
      float a0r=ar[r0], a0i=ai[r0], a1r=ar[r1], a1i=ai[r1];
      ar[r0] =  m00r*a0r - m00i*a0i + m01r*a1r - m01i*a1i;
      ai[r0] =  m00r*a0i + m00i*a0r + m01r*a1i + m01i*a1r;
      ar[r1] = -m01r*a0r - m01i*a0i + m00r*a1r + m00i*a1i;
      ai[r1] = -m01r*a0i + m01i*a0r + m00r*a1i - m00i*a1r;
    }
  }
}
__device__ __forceinline__ void cry_cross(float* ar, float* ai, int lane,
                                          int shc, int sht, float cc, float sc) {
  const int lm = 1 << sht;
  const int ctrl = (lane >> shc) & 1;
  const float ce = ctrl ? cc : 1.0f;
  float se = ((lane >> sht) & 1) ? sc : -sc;
  se = ctrl ? se : 0.0f;
#pragma unroll
  for (int r = 0; r < 4; ++r) {
    float pr = __shfl_xor(ar[r], lm, 64);
    float pi = __shfl_xor(ai[r], lm, 64);
    ar[r] = ce*ar[r] + se*pr;
    ai[r] = ce*ai[r] + se*pi;
  }
}
__device__ __forceinline__ void cry_local(float* ar, float* ai, int lane,
                                          int shc, int pt, float cc, float sc) {
  const int ctrl = (lane >> shc) & 1;
  const float ce = ctrl ? cc : 1.0f;
  const float se = ctrl ? sc : 0.0f;
  const int m = 1 << pt;
#pragma unroll
  for (int r0 = 0; r0 < 4; ++r0) {
    if (!(r0 & m)) {
      const int r1 = r0 | m;
      float a0r=ar[r0], a0i=ai[r0], a1r=ar[r1], a1i=ai[r1];
      ar[r0] = ce*a0r - se*a1r;  ai[r0] = ce*a0i - se*a1i;
      ar[r1] = ce*a1r + se*a0r;  ai[r1] = ce*a1i + se*a0i;
    }
  }
}
__device__ __forceinline__ void ry_pair23(float* ar, float* ai, float cc, float sc) {
  float a0r=ar[2], a0i=ai[2], a1r=ar[3], a1i=ai[3];
  ar[2] = cc*a0r - sc*a1r;  ai[2] = cc*a0i - sc*a1i;
  ar[3] = cc*a1r + sc*a0r;  ai[3] = cc*a1i + sc*a0i;
}
__device__ __forceinline__ void crx_cross(float* ar, float* ai, int lane,
                                          int shc, int sht, float cc, float sc) {
  const int lm = 1 << sht;
  const int ctrl = (lane >> shc) & 1;
  const float ce = ctrl ? cc : 1.0f;
  const float se = ctrl ? sc : 0.0f;
#pragma unroll
  for (int r = 0; r < 4; ++r) {
    float pr = __shfl_xor(ar[r], lm, 64);
    float pi = __shfl_xor(ai[r], lm, 64);
    ar[r] = ce*ar[r] + se*pi;
    ai[r] = ce*ai[r] - se*pr;
  }
}
__device__ __forceinline__ void crx_local(float* ar, float* ai, int lane,
                                          int shc, int pt, float cc, float sc) {
  const int ctrl = (lane >> shc) & 1;
  const float ce = ctrl ? cc : 1.0f;
  const float se = ctrl ? sc : 0.0f;
  const int m = 1 << pt;
#pragma unroll
  for (int r0 = 0; r0 < 4; ++r0) {
    if (!(r0 & m)) {
      const int r1 = r0 | m;
      float a0r=ar[r0], a0i=ai[r0], a1r=ar[r1], a1i=ai[r1];
      ar[r0] = ce*a0r + se*a1i;  ai[r0] = ce*a0i - se*a1r;
      ar[r1] = ce*a1r + se*a0i;  ai[r1] = ce*a1i - se*a0r;
    }
  }
}
__device__ __forceinline__ void rx_pair23(float* ar, float* ai, float cc, float sc) {
  float a0r=ar[2], a0i=ai[2], a1r=ar[3], a1i=ai[3];
  ar[2] = cc*a0r + sc*a1i;  ai[2] = cc*a0i - sc*a1r;
  ar[3] = cc*a1r + sc*a0i;  ai[3] = cc*a1i - sc*a0r;
}

__device__ __forceinline__ unsigned short f2bf(float f) {
  unsigned int u = __float_as_uint(f);
  u = (u + 0x7FFFu + ((u >> 16) & 1u)) >> 16;
  return (unsigned short)u;
}

typedef __attribute__((ext_vector_type(8))) short bf16x8;
typedef __attribute__((ext_vector_type(4))) float f32x4;

// Complex 16x16-tile GEMM body (verified R4): C = A*B with column-major
// complex buffers: bufA[k*512 + i*2] = A[i][k], bufB[j*512 + k*2] = B[k][j].
__device__ __forceinline__ void cgemm_tile(const float* __restrict__ bufA,
                                           const float* __restrict__ bufB,
                                           int bi, int bj, int tid,
                                           float& accr, float& acci,
                                           float2* S2 /*32*16*/, float2* S1 /*16*33*/) {
  const int ti = tid & 15;
  const int tj = tid >> 4;
  accr = 0.f; acci = 0.f;
#pragma unroll 1
  for (int kt = 0; kt < 8; ++kt) {
    __syncthreads();
#pragma unroll
    for (int v = 0; v < 2; ++v) {
      const int s = v * 256 + tid;
      const int k = s >> 4, i = s & 15;
      S2[k * 16 + i] = *(const float2*)(bufA + (size_t)(kt*32 + k) * 512 + (bi*16 + i) * 2);
      const int j2 = s >> 5, k2 = s & 31;
      S1[j2 * 33 + k2] = *(const float2*)(bufB + (size_t)(bj*16 + j2) * 512 + (kt*32 + k2) * 2);
    }
    __syncthreads();
#pragma unroll
    for (int kk = 0; kk < 32; ++kk) {
      const float2 a = S2[kk * 16 + ti];
      const float2 b = S1[tj * 33 + kk];
      accr = fmaf(a.x, b.x, accr);  accr = fmaf(-a.y, b.y, accr);
      acci = fmaf(a.x, b.y, acci);  acci = fmaf(a.y, b.x, acci);
    }
  }
}

} // namespace

// ---------------- K1: build per-layer unitaries ----------------
// block = (layer l, basis s0); 1 wave. Writes Ul^T as complex pairs:
// Uq[(l*256+s0)*512 + o*2] = re, +1 = im  (U_l[o][s0]).
__global__ __launch_bounds__(64) void build_quarter(const float* __restrict__ qw,
                                                    float* __restrict__ Uq) {
  __shared__ float4 sM[24];
  const int lane = threadIdx.x;
  const int l    = blockIdx.x >> 8;
  const int s0   = blockIdx.x & 255;

  if (lane < 24) {
    const int j = lane >> 3;
    const int q = lane & 7;
    float a, bb;
    if (j == 0) {        // M0 = RY(qw[l][q]) * RZ(qw[l-1][124+q])
      a  = qw[l * NW_L + q];
      bb = (l > 0) ? qw[(l - 1) * NW_L + 124 + q] : 0.f;
    } else if (j == 1) { // M1 = RX(44+q) * RY(36+q)
      a  = qw[l * NW_L + 44 + q];
      bb = qw[l * NW_L + 36 + q];
    } else {             // M2 = RZ(88+q) * RX(80+q); RZ dropped at l=3 (trailing diag)
      a  = (l < 3) ? qw[l * NW_L + 88 + q] : 0.f;
      bb = qw[l * NW_L + 80 + q];
    }
    float sa, ca, sb, cb;
    __sincosf(0.5f * a,  &sa, &ca);
    __sincosf(0.5f * bb, &sb, &cb);
    float4 m;
    if (j == 0)      m = make_float4(ca*cb, -ca*sb, -sa*cb, -sa*sb); // RY*RZ
    else if (j == 1) m = make_float4(ca*cb, -sa*sb, -ca*sb, -sa*cb); // RX*RY
    else             m = make_float4(ca*cb, -sa*cb, -sb*sa, -sb*ca); // RZ*RX
    sM[lane] = m;
  }

  float ar[4], ai[4];
#pragma unroll
  for (int r = 0; r < 4; ++r) {
    ar[r] = (((lane << 2) | r) == s0) ? 1.f : 0.f;
    ai[r] = 0.f;
  }
  float dzr[4], dzi[4];
#pragma unroll
  for (int r = 0; r < 4; ++r) {
    const int s = (lane << 2) | r;
    dzr[r] = D_CRZ.v[2*s];
    dzi[r] = D_CRZ.v[2*s+1];
  }
  __syncthreads();

  // one layer: M0, CRY, M1, CRX, M2, (CRZ diag if l<3)
#pragma unroll
  for (int q = 0; q < 8; ++q) {
    float4 m = sM[q];
    if (q <= 5) gen_cross(ar, ai, lane, 5 - q, m.x, m.y, m.z, m.w);
    else        gen_local(ar, ai, 7 - q, m.x, m.y, m.z, m.w);
  }
#pragma unroll
  for (int i = 0; i < 28; ++i) {
    const int c = PC[i], t = PT[i];
    const float cc = T_CRY.c[i], sc = T_CRY.s[i];
    if (t <= 5)      cry_cross(ar, ai, lane, 5 - c, 5 - t, cc, sc);
    else if (c <= 5) cry_local(ar, ai, lane, 5 - c, 7 - t, cc, sc);
    else             ry_pair23(ar, ai, cc, sc);
  }
#pragma unroll
  for (int q = 0; q < 8; ++q) {
    float4 m = sM[8 + q];
    if (q <= 5) gen_cross(ar, ai, lane, 5 - q, m.x, m.y, m.z, m.w);
    else        gen_local(ar, ai, 7 - q, m.x, m.y, m.z, m.w);
  }
#pragma unroll
  for (int i = 0; i < 28; ++i) {
    const int c = PC[i], t = PT[i];
    const float cc = T_CRX.c[i], sc = T_CRX.s[i];
    if (t <= 5)      crx_cross(ar, ai, lane, 5 - c, 5 - t, cc, sc);
    else if (c <= 5) crx_local(ar, ai, lane, 5 - c, 7 - t, cc, sc);
    else             rx_pair23(ar, ai, cc, sc);
  }
#pragma unroll
  for (int q = 0; q < 8; ++q) {
    float4 m = sM[16 + q];
    if (q <= 5) gen_cross(ar, ai, lane, 5 - q, m.x, m.y, m.z, m.w);
    else        gen_local(ar, ai, 7 - q, m.x, m.y, m.z, m.w);
  }
  if (l < 3) {
#pragma unroll
    for (int r = 0; r < 4; ++r) {
      float mr = ar[r], mi = ai[r];
      ar[r] = mr*dzr[r] - mi*dzi[r];
      ai[r] = mr*dzi[r] + mi*dzr[r];
    }
  }

  float4* dst = (float4*)(Uq + (size_t)(l * 256 + s0) * 512);
  dst[2*lane]     = make_float4(ar[0], ai[0], ar[1], ai[1]);
  dst[2*lane + 1] = make_float4(ar[2], ai[2], ar[3], ai[3]);
}

// ---------------- K2: T_p = U_{2p+1} * U_{2p}, fp32 complex ----------------
__global__ __launch_bounds__(256) void combine_pair(const float* __restrict__ Uq,
                                                    float* __restrict__ Tc) {
  __shared__ float2 S2[32 * 16];
  __shared__ float2 S1[16 * 33];
  const int tid = threadIdx.x;
  const int p   = blockIdx.x >> 8;
  const int rem = blockIdx.x & 255;
  const int bi  = rem & 15;
  const int bj  = rem >> 4;
  const float* bufA = Uq + (size_t)(2*p + 1) * 256 * 512;
  const float* bufB = Uq + (size_t)(2*p) * 256 * 512;
  float accr, acci;
  cgemm_tile(bufA, bufB, bi, bj, tid, accr, acci, S2, S1);
  const int i = bi * 16 + (tid & 15), j = bj * 16 + (tid >> 4);
  *(float2*)(Tc + (size_t)p * 256 * 512 + (size_t)j * 512 + i * 2) = make_float2(accr, acci);
}

// ---------------- K3: U = T2 * T1, emit bf16 ----------------
__global__ __launch_bounds__(256) void combine_final(const float* __restrict__ Tc,
                                                     unsigned short* __restrict__ Ubf) {
  __shared__ float2 S2[32 * 16];
  __shared__ float2 S1[16 * 33];
  const int tid = threadIdx.x;
  const int bi  = blockIdx.x & 15;
  const int bj  = blockIdx.x >> 4;
  const float* bufA = Tc + (size_t)256 * 512;   // T2
  const float* bufB = Tc;                        // T1
  float accr, acci;
  cgemm_tile(bufA, bufB, bi, bj, tid, accr, acci, S2, S1);
  const int i = bi * 16 + (tid & 15), j = bj * 16 + (tid >> 4);
  Ubf[(size_t)i * 256 + j]         = f2bf(accr);
  Ubf[(size_t)(i + 256) * 256 + j] = f2bf(acci);
}

// ---------------- K4: amps = U x via MFMA + fused epilogue ----------------
__global__ __launch_bounds__(256) void mfma_eval(const float* __restrict__ x,
                                                 const unsigned short* __restrict__ Ubf,
                                                 const float* __restrict__ fcw,
                                                 const float* __restrict__ fcb,
                                                 float* __restrict__ out) {
  __shared__ unsigned short Xs[16 * 264];   // [col][k] bf16, padded
  __shared__ float Zp[4][16][9];
  __shared__ float Zf[16][9];
  const int tid  = threadIdx.x;
  const int lane = tid & 63;
  const int w    = tid >> 6;
  const int colbase = blockIdx.x * 16;

  // stage x tile -> bf16: float4 reads (cols c4..c4+3 at row k), 4 passes
#pragma unroll
  for (int pass = 0; pass < 4; ++pass) {
    const int k  = pass * 64 + (tid >> 2);
    const int c4 = (tid & 3) * 4;
    const float4 v = *(const float4*)(x + (size_t)k * NSAMP + colbase + c4);
    Xs[(c4 + 0) * 264 + k] = f2bf(v.x);
    Xs[(c4 + 1) * 264 + k] = f2bf(v.y);
    Xs[(c4 + 2) * 264 + k] = f2bf(v.z);
    Xs[(c4 + 3) * 264 + k] = f2bf(v.w);
  }
  __syncthreads();

  const int quad = lane >> 4;
  const int n    = lane & 15;
  f32x4 acc[8];
#pragma unroll
  for (int rt = 0; rt < 8; ++rt) acc[rt] = (f32x4){0.f, 0.f, 0.f, 0.f};
  const int rowb = w * 128;

#pragma unroll
  for (int kt = 0; kt < 8; ++kt) {
    const bf16x8 bfrag = *(const bf16x8*)&Xs[n * 264 + kt * 32 + quad * 8];
#pragma unroll
    for (int rt = 0; rt < 8; ++rt) {
      const int row = rowb + rt * 16 + n;
      const bf16x8 afrag = *(const bf16x8*)(Ubf + (size_t)row * 256 + kt * 32 + quad * 8);
      acc[rt] = __builtin_amdgcn_mfma_f32_16x16x32_bf16(afrag, bfrag, acc[rt], 0, 0, 0);
    }
  }

  // epilogue (verified R4): amp at (row = w*128 + rt*16 + quad*4 + reg, col = n)
  float za[9];
#pragma unroll
  for (int i = 0; i < 9; ++i) za[i] = 0.f;
  const float m4 = (lane & 32) ? -1.f : 1.f;
  const float m5 = (lane & 16) ? -1.f : 1.f;
#pragma unroll
  for (int rt = 0; rt < 8; ++rt) {
#pragma unroll
    for (int reg = 0; reg < 4; ++reg) {
      const float v = acc[rt][reg];
      const float p = v * v;
      za[0] += p;
      za[1] += (w  & 1) ? -p : p;
      za[2] += (rt & 4) ? -p : p;
      za[3] += (rt & 2) ? -p : p;
      za[4] += (rt & 1) ? -p : p;
      za[5] = fmaf(m4, p, za[5]);
      za[6] = fmaf(m5, p, za[6]);
      za[7] += (reg & 2) ? -p : p;
      za[8] += (reg & 1) ? -p : p;
    }
  }
#pragma unroll
  for (int off = 16; off <= 32; off <<= 1) {
#pragma unroll
    for (int i = 0; i < 9; ++i) za[i] += __shfl_xor(za[i], off, 64);
  }
  if (lane < 16) {
#pragma unroll
    for (int i = 0; i < 9; ++i) Zp[w][lane][i] = za[i];
  }
  __syncthreads();

  if (tid < 144) {
    const int col = tid / 9, q = tid - col * 9;
    Zf[col][q] = Zp[0][col][q] + Zp[1][col][q] + Zp[2][col][q] + Zp[3][col][q];
  }
  __syncthreads();

  if (tid < 112) {
    const int col = tid / 7, oo = tid - col * 7;
    const float inv = 1.f / Zf[col][0];
    float v = fcb[oo];
#pragma unroll
    for (int q = 0; q < 8; ++q)
      v = fmaf(fcw[oo * 8 + q], Zf[col][1 + q] * inv, v);
    out[(size_t)(colbase + col) * 7 + oo] = v;
  }
}

extern "C" void kernel_launch(void* const* d_in, const int* in_sizes, int n_in,
                              void* d_out, int out_size, void* d_ws, size_t ws_size,
                              hipStream_t stream) {
  const float* x   = (const float*)d_in[0];   // [256, 4096]
  const float* qw  = (const float*)d_in[1];   // [4, 132]
  const float* fcw = (const float*)d_in[2];   // [7, 8]
  const float* fcb = (const float*)d_in[3];   // [7]
  float* out = (float*)d_out;                 // [4096, 7]

  float* Uq = (float*)d_ws;                             // 4 x 256x256 complex fp32 (2 MB)
  float* Tc = Uq + (size_t)4 * 256 * 512;               // 2 x 256x256 complex fp32 (1 MB)
  unsigned short* Ubf = (unsigned short*)(Tc + (size_t)2 * 256 * 512);  // 512x256 bf16

  hipLaunchKernelGGL(build_quarter, dim3(1024), dim3(64),  0, stream, qw, Uq);
  hipLaunchKernelGGL(combine_pair,  dim3(512),  dim3(256), 0, stream, Uq, Tc);
  hipLaunchKernelGGL(combine_final, dim3(256),  dim3(256), 0, stream, Tc, Ubf);
  hipLaunchKernelGGL(mfma_eval,     dim3(256),  dim3(256), 0, stream, x, Ubf, fcw, fcb, out);
}